// Round 10
// baseline (1110.680 us; speedup 1.0000x reference)
//
#include <hip/hip_runtime.h>

// Batched box-QP via ADMM (rho=1, 50 iters). One 1024-thread block per batch.
// M = Q + I (SPD) inverted in LDS by a RANK-4 blocked symmetric sweep on the
// packed quad-padded lower triangle (R2 skeleton: 56 VGPR, no spill, proven).
//
// R10 layout surgery on R2 (which measured 362us with 4.2e7 conflicts):
//  - PT[4][264] transposed panel: Schur P-reads lane-contiguous b128 (was
//    64B-stride -> 2-bank, 16-way conflict = R2's dominant conflict source).
//  - WT[4][264]: pivot-row writeback reads contiguous (was 16-way gather).
//  - triq XOR swizzle (dword a ^= (a>>3)&28) on the triangle: spreads the
//    quadratic row-base strides (phase-1 / matvec-lower) to <=4-way.
//  - matvec: wave-uniform chunk roles (q4 = t>>8), rhs reads broadcast,
//    upper-chunk scalars lane-consecutive, part[] LDS reduction.
// Every phase keeps <=~30 live VGPRs (the 1024-thread budget is 64: R3-R8).

#define NX     256
#define NITER  50
#define NTHR   1024

#define OFF_PT  33280                 // PT[4][264]
#define OFF_W4  (OFF_PT + 4 * 264)   // 34336: W4[256] float4 (16B aligned)
#define OFF_WT  (OFF_W4 + 1024)      // 35360: WT[4][264]
#define LDS_F   (OFF_WT + 4 * 264)   // 36416 floats = 145664 B
// matvec aliases: part = lds+OFF_PT (1024 f), vbuf = part+1024 (256 f)

__host__ __device__ constexpr int rowoff(int r) {   // packed row offset (floats)
    return 4 * ((r >> 2) + 1) * (((r >> 2) << 1) + (r & 3));
}
// triangle swizzle: quad q -> q ^ ((q>>3)&7); dword form below (consistent)
__device__ __forceinline__ int triq(int q) { return q ^ ((q >> 3) & 7); }
__device__ __forceinline__ int triF(int a) { return a ^ ((a >> 3) & 28); }

__device__ __forceinline__ int tile_rb(int s) {     // row-major triangular tile
    int r = (int)((sqrtf(8.0f * (float)s + 1.0f) - 1.0f) * 0.5f);
    while ((r + 1) * (r + 2) / 2 <= s) ++r;
    while (r * (r + 1) / 2 > s) --r;
    return r;
}

template <int J0>
__device__ __forceinline__ float chunk_upper_f(const float* tri, const float* vb, int rr) {
    float a0 = 0.f, a1 = 0.f, a2 = 0.f, a3 = 0.f;
    #pragma unroll
    for (int jj = 0; jj < 64; jj += 4) {   // addr = const + rr: lane-consecutive
        a0 += tri[triF(rowoff(J0 + jj + 0) + rr)] * vb[J0 + jj + 0];
        a1 += tri[triF(rowoff(J0 + jj + 1) + rr)] * vb[J0 + jj + 1];
        a2 += tri[triF(rowoff(J0 + jj + 2) + rr)] * vb[J0 + jj + 2];
        a3 += tri[triF(rowoff(J0 + jj + 3) + rr)] * vb[J0 + jj + 3];
    }
    return (a0 + a1) + (a2 + a3);
}
template <int J0>
__device__ __forceinline__ float chunk_mixed_f(const float* tri, const float* vb, int rr) {
    const int ror = rowoff(rr);
    float a0 = 0.f, a1 = 0.f, a2 = 0.f, a3 = 0.f;
    #pragma unroll
    for (int jj = 0; jj < 64; jj += 4) {
        {   const int j = J0 + jj + 0;
            a0 += tri[triF((j <= rr) ? (ror + j) : (rowoff(j) + rr))] * vb[j]; }
        {   const int j = J0 + jj + 1;
            a1 += tri[triF((j <= rr) ? (ror + j) : (rowoff(j) + rr))] * vb[j]; }
        {   const int j = J0 + jj + 2;
            a2 += tri[triF((j <= rr) ? (ror + j) : (rowoff(j) + rr))] * vb[j]; }
        {   const int j = J0 + jj + 3;
            a3 += tri[triF((j <= rr) ? (ror + j) : (rowoff(j) + rr))] * vb[j]; }
    }
    return (a0 + a1) + (a2 + a3);
}
__device__ __forceinline__ float chunk_lower_f(const float4* tri4, const float* vb,
                                               int rowq, int q4) {
    const int qb = rowq + (q4 << 4);
    const float* vbp = vb + (q4 << 6);
    float a0 = 0.f, a1 = 0.f, a2 = 0.f, a3 = 0.f;
    #pragma unroll
    for (int m = 0; m < 16; ++m) {
        const float4 A = tri4[triq(qb + m)];
        const float4 V = *(const float4*)(vbp + 4 * m);   // broadcast (free)
        a0 += A.x * V.x; a1 += A.y * V.y; a2 += A.z * V.z; a3 += A.w * V.w;
    }
    return (a0 + a1) + (a2 + a3);
}

__global__ void __launch_bounds__(NTHR, 1)
boxqp_r10_kernel(const float* __restrict__ Q,
                 const float* __restrict__ p,
                 const float* __restrict__ lb,
                 const float* __restrict__ ub,
                 float* __restrict__ out)
{
    __shared__ __align__(16) float lds[LDS_F];
    float*  tri  = lds;
    float4* tri4 = (float4*)lds;
    float*  PT   = lds + OFF_PT;                  // P^T [4][264]
    float4* W4   = (float4*)(lds + OFF_W4);       // W row-major [256]
    float*  WT   = lds + OFF_WT;                  // W^T [4][264]
    float*  part = lds + OFF_PT;                  // matvec alias (1024 f)
    float*  vbuf = lds + OFF_PT + 1024;           // matvec alias (256 f)
    unsigned char* qrow = (unsigned char*)(lds + OFF_PT);   // load alias (8320 B)

    const int t = threadIdx.x;
    const int b = blockIdx.x;
    const size_t qbase = ((size_t)b) << 16;       // b*256*256

    // --- per-thread tile descriptors (2 each; t<32 a third) ---
    const int rb0 = tile_rb(t),        cb0 = t        - ((rb0 * (rb0 + 1)) >> 1);
    const int rb1 = tile_rb(t + 1024), cb1 = t + 1024 - ((rb1 * (rb1 + 1)) >> 1);
    const int s2i = (t < 32) ? (t + 2048) : 2048;
    const int rb2 = tile_rb(s2i),      cb2 = s2i      - ((rb2 * (rb2 + 1)) >> 1);

    // --- qrow LUT (packed quad -> row), then coalesced load of M = Q + I ---
    if (t < 256) {
        const int bq = rowoff(t) >> 2, nq = (t >> 2) + 1;
        for (int m = 0; m < nq; ++m) qrow[bq + m] = (unsigned char)t;
    }
    __syncthreads();
    for (int q = t; q < 8320; q += NTHR) {
        const int r  = qrow[q];
        const int ro = rowoff(r) >> 2;
        const int cq = q - ro;
        float4 v = *(const float4*)(Q + qbase + ((size_t)r << 8) + (cq << 2));
        if (cq == (r >> 2)) {                     // diagonal quad: zero upper, +I
            const int c0 = cq << 2;
            v.x = (c0 + 0 > r) ? 0.f : (v.x + (c0 + 0 == r ? 1.f : 0.f));
            v.y = (c0 + 1 > r) ? 0.f : (v.y + (c0 + 1 == r ? 1.f : 0.f));
            v.z = (c0 + 2 > r) ? 0.f : (v.z + (c0 + 2 == r ? 1.f : 0.f));
            v.w = (c0 + 3 > r) ? 0.f : (v.w + (c0 + 3 == r ? 1.f : 0.f));
        }
        tri4[triq(q)] = v;
    }
    __syncthreads();

    const int i1 = t & 255;          // phase-1 row
    const int m1 = t >> 8;           // phase-1 panel column (wave-uniform)

    // --- phase-3 worker ---
    auto update_tile = [&](int rb, int cb, int kb, const float S[4][4]) {
        const int r0 = rb << 2, j0 = cb << 2;
        int roQ[4];
        #pragma unroll
        for (int s2 = 0; s2 < 4; ++s2) roQ[s2] = rowoff(r0 + s2) >> 2;

        if (rb == kb) {
            if (cb == kb) {                       // pivot block <- S (per-thread)
                #pragma unroll
                for (int s2 = 0; s2 < 4; ++s2)
                    tri4[triq(roQ[s2] + cb)] =
                        make_float4(S[s2][0], S[s2][1], S[s2][2], S[s2][3]);
            } else {                              // pivot rows <- W^T (contig)
                #pragma unroll
                for (int s2 = 0; s2 < 4; ++s2)
                    tri4[triq(roQ[s2] + cb)] = *(const float4*)(WT + s2 * 264 + j0);
            }
        } else if (cb == kb) {                    // panel <- W (broadcast read)
            #pragma unroll
            for (int s2 = 0; s2 < 4; ++s2)
                tri4[triq(roQ[s2] + cb)] = W4[r0 + s2];
        } else {                                  // Schur: A -= W * P^T
            const float4 p0 = *(const float4*)(PT + 0 * 264 + j0);
            const float4 p1 = *(const float4*)(PT + 1 * 264 + j0);
            const float4 p2 = *(const float4*)(PT + 2 * 264 + j0);
            const float4 p3 = *(const float4*)(PT + 3 * 264 + j0);
            #pragma unroll
            for (int s2 = 0; s2 < 4; ++s2) {
                const float4 wr = W4[r0 + s2];    // broadcast (free)
                float4 a = tri4[triq(roQ[s2] + cb)];
                a.x -= wr.x * p0.x + wr.y * p1.x + wr.z * p2.x + wr.w * p3.x;
                a.y -= wr.x * p0.y + wr.y * p1.y + wr.z * p2.y + wr.w * p3.y;
                a.z -= wr.x * p0.z + wr.y * p1.z + wr.z * p2.z + wr.w * p3.z;
                a.w -= wr.x * p0.w + wr.y * p1.w + wr.z * p2.w + wr.w * p3.w;
                tri4[triq(roQ[s2] + cb)] = a;
            }
        }
    };

    // --- rank-4 blocked sweep: 64 steps; tri becomes -(M^{-1}) ---
    for (int kb = 0; kb < 64; ++kb) {
        const int k0 = kb << 2;

        // phase 1: 1024 threads, element (i1, k0+m1) -> PT[m1][i1]
        {
            const int km = k0 + m1;
            const float v = (km <= i1) ? tri[triF(rowoff(i1) + km)]
                                       : tri[triF(rowoff(km) + i1)];
            PT[m1 * 264 + i1] = v;
        }
        __syncthreads();

        // every thread: redundant 4x4 pivot sweep in registers -> S = -(D^{-1})
        float S[4][4];
        #pragma unroll
        for (int mm = 0; mm < 4; ++mm) {
            #pragma unroll
            for (int c = 0; c < 4; ++c) S[mm][c] = PT[c * 264 + k0 + mm];
        }
        #pragma unroll
        for (int kk = 0; kk < 4; ++kk) {
            const float inv = 1.0f / S[kk][kk];
            #pragma unroll
            for (int a2 = 0; a2 < 4; ++a2) {
                if (a2 == kk) continue;
                #pragma unroll
                for (int b2 = 0; b2 < 4; ++b2) {
                    if (b2 == kk) continue;
                    S[a2][b2] -= S[a2][kk] * S[kk][b2] * inv;
                }
            }
            #pragma unroll
            for (int a2 = 0; a2 < 4; ++a2) {
                if (a2 == kk) continue;
                S[a2][kk] *= inv;
                S[kk][a2] *= inv;
            }
            S[kk][kk] = -inv;
        }

        // phase 2 (t<256): W[t][:] = -(P[t]·S) -> W4 + WT
        if (t < 256) {
            const float pv0 = PT[0 * 264 + t], pv1 = PT[1 * 264 + t];
            const float pv2 = PT[2 * 264 + t], pv3 = PT[3 * 264 + t];
            const float w0 = -(pv0 * S[0][0] + pv1 * S[1][0] + pv2 * S[2][0] + pv3 * S[3][0]);
            const float w1 = -(pv0 * S[0][1] + pv1 * S[1][1] + pv2 * S[2][1] + pv3 * S[3][1]);
            const float w2 = -(pv0 * S[0][2] + pv1 * S[1][2] + pv2 * S[2][2] + pv3 * S[3][2]);
            const float w3 = -(pv0 * S[0][3] + pv1 * S[1][3] + pv2 * S[2][3] + pv3 * S[3][3]);
            W4[t] = make_float4(w0, w1, w2, w3);
            WT[0 * 264 + t] = w0; WT[1 * 264 + t] = w1;
            WT[2 * 264 + t] = w2; WT[3 * 264 + t] = w3;
        }
        __syncthreads();

        // phase 3: 2 tiles per thread (+1 for t<32)
        update_tile(rb0, cb0, kb, S);
        update_tile(rb1, cb1, kb, S);
        if (t < 32) update_tile(rb2, cb2, kb, S);
        __syncthreads();
    }

    // --- ADMM iterations: x = tri·vbuf (tri = -Minv, vbuf = u+p-z = -rhs) ---
    const int rr   = t & 255;
    const int q4   = t >> 8;           // wave-uniform chunk id
    const int sw   = (t >> 6) & 3;     // wave-uniform row sub-block
    const int rowq = rowoff(rr) >> 2;

    float x = 0.f, z = 0.f, uu = 0.f;
    float pi = 0.f, lbi = 0.f, ubi = 0.f;
    if (t < 256) {
        const int gb = (b << 8) + t;
        pi = p[gb]; lbi = lb[gb]; ubi = ub[gb];
        vbuf[t] = pi;                  // z=u=0 -> vbuf = p
    }
    __syncthreads();

    for (int it = 0; it < NITER; ++it) {
        float acc;
        if (sw > q4) {
            acc = chunk_lower_f(tri4, vbuf, rowq, q4);
        } else if (sw == q4) {
            switch (q4) {
                case 0:  acc = chunk_mixed_f<0  >(tri, vbuf, rr); break;
                case 1:  acc = chunk_mixed_f<64 >(tri, vbuf, rr); break;
                case 2:  acc = chunk_mixed_f<128>(tri, vbuf, rr); break;
                default: acc = chunk_mixed_f<192>(tri, vbuf, rr); break;
            }
        } else {
            switch (q4) {
                case 1:  acc = chunk_upper_f<64 >(tri, vbuf, rr); break;
                case 2:  acc = chunk_upper_f<128>(tri, vbuf, rr); break;
                default: acc = chunk_upper_f<192>(tri, vbuf, rr); break;
            }
        }
        part[(q4 << 8) | rr] = acc;
        __syncthreads();
        if (t < 256) {
            x = part[t] + part[256 + t] + part[512 + t] + part[768 + t];
            const float xu = x + uu;
            z  = fminf(fmaxf(xu, lbi), ubi);
            uu = xu - z;
            vbuf[t] = (uu + pi) - z;
        }
        __syncthreads();
    }

    if (t < 256) out[(b << 8) + t] = x;
}

extern "C" void kernel_launch(void* const* d_in, const int* in_sizes, int n_in,
                              void* d_out, int out_size, void* d_ws, size_t ws_size,
                              hipStream_t stream) {
    const float* Q  = (const float*)d_in[0];
    const float* p  = (const float*)d_in[1];
    const float* lb = (const float*)d_in[2];
    const float* ub = (const float*)d_in[3];
    float* out = (float*)d_out;

    hipLaunchKernelGGL(boxqp_r10_kernel, dim3(256), dim3(NTHR), 0, stream,
                       Q, p, lb, ub, out);
}